// Round 1
// baseline (683.457 us; speedup 1.0000x reference)
//
#include <hip/hip_runtime.h>

// Problem constants (from reference)
#define NE    8
#define KDIM  2048
#define NDIM  5632
#define NTOK  4096
#define CAP   512      // tokens per expert (balanced routing, = NTOK/NE)
#define NGRP  32       // KDIM / GROUP_SIZE(64)
#define BM    128
#define BN    128
#define BK    32
#define MT    4        // CAP / BM
#define NT    44       // NDIM / BN
#define LDSS  40       // padded LDS row stride in bf16 elems (32 -> 40: 80B = 20 banks, 16B-aligned)

typedef __attribute__((ext_vector_type(8))) short bf16x8;
typedef __attribute__((ext_vector_type(4))) short bf16x4;
typedef __attribute__((ext_vector_type(4))) float f32x4;

// fp32 -> bf16 round-to-nearest-even (finite inputs only)
static __device__ __forceinline__ short f2bf(float f) {
    union { float f; unsigned u; } x; x.f = f;
    unsigned r = (x.u + 0x7fffu + ((x.u >> 16) & 1u)) >> 16;
    return (short)r;
}

__global__ __launch_bounds__(256, 2)
void hqq_gemm_kernel(const float* __restrict__ inp,
                     const int*   __restrict__ wq,
                     const float* __restrict__ sz,
                     float*       __restrict__ out)
{
    // Block mapping: expert-major (LLC locality for weights: 46 MB/expert << 256 MB L3),
    // mt fastest (4 consecutive blocks share one B tile -> L2 hits on weights).
    const int bid = blockIdx.x;
    const int e   = bid / (MT * NT);
    const int rem = bid % (MT * NT);
    const int nt  = rem >> 2;
    const int mt  = rem & 3;

    __shared__ __align__(16) short Alds[BM * LDSS];  // [m][k] bf16
    __shared__ __align__(16) short Blds[BN * LDSS];  // [n][k] bf16 (transposed)

    const int tid = threadIdx.x;
    const int m0  = e * CAP + mt * BM;   // global token row base
    const int n0  = nt * BN;

    // A staging: 8 k-quads x 32 rows, loop 4 passes of rows
    const int a_kq  = tid & 7;
    const int a_row = tid >> 3;
    // B staging: thread owns one n column, two k-octets
    const int b_n   = tid & 127;
    const int b_h   = tid >> 7;

    const float* Ab  = inp + (size_t)m0 * KDIM;
    const int*   Wb  = wq  + (size_t)e * KDIM * NDIM + n0 + b_n;
    const float* SZb = sz  + (size_t)e * NGRP * (NDIM * 2) + (size_t)(n0 + b_n) * 2;

    f32x4 acc[4][4];
    #pragma unroll
    for (int i = 0; i < 4; ++i)
        #pragma unroll
        for (int j = 0; j < 4; ++j)
            acc[i][j] = (f32x4){0.f, 0.f, 0.f, 0.f};

    const int wave = tid >> 6;
    const int lane = tid & 63;
    const int wm = (wave >> 1) << 6;   // wave row origin in tile
    const int wn = (wave & 1) << 6;    // wave col origin in tile
    const int lr = lane & 15;          // A row / B col / D col
    const int lq = lane >> 4;          // quad

    for (int k0 = 0; k0 < KDIM; k0 += BK) {
        const int g = k0 >> 6;  // quant group (constant within a BK=32 step)

        // ---- stage A: BM x BK fp32 -> bf16, [m][k] ----
        #pragma unroll
        for (int p = 0; p < 4; ++p) {
            const int row = a_row + p * 32;
            const float4 v = *(const float4*)(Ab + (size_t)row * KDIM + k0 + a_kq * 4);
            bf16x4 h;
            h[0] = f2bf(v.x); h[1] = f2bf(v.y); h[2] = f2bf(v.z); h[3] = f2bf(v.w);
            *(bf16x4*)&Alds[row * LDSS + a_kq * 4] = h;
        }

        // ---- stage B: BK x BN int codes -> dequant bf16, transposed to [n][k] ----
        const float2 s2 = *(const float2*)(SZb + (size_t)g * (NDIM * 2));
        const float s  = s2.x;
        const float z8 = s2.y - 8.f * s2.x;   // w = q*s + (z - 8s)
        #pragma unroll
        for (int oo = 0; oo < 2; ++oo) {
            const int ko = b_h * 8 + oo * 16;
            const int* wp = Wb + (size_t)(k0 + ko) * NDIM;
            bf16x8 bb;
            #pragma unroll
            for (int j = 0; j < 8; ++j) {
                const float q = (float)wp[(size_t)j * NDIM];  // lanes: consecutive n -> coalesced
                bb[j] = f2bf(fmaf(q, s, z8));
            }
            *(bf16x8*)&Blds[b_n * LDSS + ko] = bb;  // one ds_write_b128
        }

        __syncthreads();

        // ---- compute: 8 ds_read_b128 + 16 MFMA per wave ----
        bf16x8 af[4], bfv[4];
        #pragma unroll
        for (int i = 0; i < 4; ++i)
            af[i] = *(const bf16x8*)&Alds[(wm + i * 16 + lr) * LDSS + lq * 8];
        #pragma unroll
        for (int j = 0; j < 4; ++j)
            bfv[j] = *(const bf16x8*)&Blds[(wn + j * 16 + lr) * LDSS + lq * 8];
        #pragma unroll
        for (int i = 0; i < 4; ++i)
            #pragma unroll
            for (int j = 0; j < 4; ++j)
                acc[i][j] = __builtin_amdgcn_mfma_f32_16x16x32_bf16(af[i], bfv[j], acc[i][j], 0, 0, 0);

        __syncthreads();
    }

    // ---- epilogue: C/D layout row=(lane>>4)*4+reg, col=lane&15 ----
    const int orow0 = m0 + wm + lq * 4;
    const int ocol0 = n0 + wn + lr;
    #pragma unroll
    for (int i = 0; i < 4; ++i)
        #pragma unroll
        for (int r = 0; r < 4; ++r) {
            float* op = out + (size_t)(orow0 + i * 16 + r) * NDIM + ocol0;
            #pragma unroll
            for (int j = 0; j < 4; ++j)
                op[j * 16] = acc[i][j][r];
        }
}

extern "C" void kernel_launch(void* const* d_in, const int* in_sizes, int n_in,
                              void* d_out, int out_size, void* d_ws, size_t ws_size,
                              hipStream_t stream) {
    const float* inp = (const float*)d_in[0];
    // d_in[1] = tokens_per_expert: balanced routing (NTOK/NE each) per setup; capacity
    // semantics of the reference make expert e own rows [e*CAP, (e+1)*CAP). Unused.
    const int*   wq  = (const int*)d_in[2];
    const float* sz  = (const float*)d_in[3];
    float*       out = (float*)d_out;

    dim3 grid(NE * MT * NT);   // 1408 blocks, expert-major
    hqq_gemm_kernel<<<grid, dim3(256), 0, stream>>>(inp, wq, sz, out);
}

// Round 2
// 674.125 us; speedup vs baseline: 1.0138x; 1.0138x over previous
//
#include <hip/hip_runtime.h>

// Problem constants (from reference)
#define NE    8
#define KDIM  2048
#define NDIM  5632
#define NTOK  4096
#define CAP   512      // tokens per expert (balanced routing, = NTOK/NE)
#define NGRP  32       // KDIM / GROUP_SIZE(64)
#define BM    128
#define BN    128
#define BK    32
#define MT    4        // CAP / BM
#define NT    44       // NDIM / BN
#define LDSS  40       // padded LDS row stride in bf16 elems (80B = 20 banks, 16B-aligned)

#define K8      (KDIM / 8)                                  // 256 packed octet-rows
#define NBLK_N  (NDIM / 256)                                // 22
#define PACK_BLOCKS (NE * K8 * NBLK_N)                      // 45056
#define ACV_BLOCKS  (NTOK * KDIM / (8 * 256))               // 4096
#define PACKED_BYTES ((size_t)NE * K8 * NDIM * 4)           // 46,137,344
#define ABF_BYTES    ((size_t)NTOK * KDIM * 2)              // 16,777,216

typedef __attribute__((ext_vector_type(8))) short bf16x8;
typedef __attribute__((ext_vector_type(4))) short bf16x4;
typedef __attribute__((ext_vector_type(4))) float f32x4;

// fp32 -> bf16 round-to-nearest-even (finite inputs only)
static __device__ __forceinline__ short f2bf(float f) {
    union { float f; unsigned u; } x; x.f = f;
    unsigned r = (x.u + 0x7fffu + ((x.u >> 16) & 1u)) >> 16;
    return (short)r;
}

// ---------------- Pass 1: pack int32 codes -> 4-bit nibbles; convert A -> bf16 ----
__global__ __launch_bounds__(256)
void pack_kernel(const int* __restrict__ wq, const float* __restrict__ inp,
                 unsigned* __restrict__ pw, unsigned short* __restrict__ abf)
{
    const int bid = blockIdx.x;
    if (bid < PACK_BLOCKS) {
        // weights: one uint32 = 8 codes along k, layout [e][k8][n]
        const int e  = bid / (K8 * NBLK_N);
        const int r  = bid % (K8 * NBLK_N);
        const int k8 = r / NBLK_N;
        const int nb = r % NBLK_N;
        const int n  = nb * 256 + threadIdx.x;
        const int* src = wq + ((size_t)e * KDIM + k8 * 8) * NDIM + n;
        unsigned v = 0;
        #pragma unroll
        for (int j = 0; j < 8; ++j)
            v |= (unsigned)(src[(size_t)j * NDIM] & 15) << (4 * j);
        pw[((size_t)e * K8 + k8) * NDIM + n] = v;   // coalesced
    } else {
        // A fp32 -> bf16, 8 elems/thread
        const size_t t = (size_t)(bid - PACK_BLOCKS) * 256 + threadIdx.x;
        const float4* p = (const float4*)inp + t * 2;
        const float4 v0 = p[0], v1 = p[1];
        bf16x8 h;
        h[0] = f2bf(v0.x); h[1] = f2bf(v0.y); h[2] = f2bf(v0.z); h[3] = f2bf(v0.w);
        h[4] = f2bf(v1.x); h[5] = f2bf(v1.y); h[6] = f2bf(v1.z); h[7] = f2bf(v1.w);
        *((bf16x8*)abf + t) = h;
    }
}

// ---------------- Pass 2: fused dequant GEMM on packed weights ----------------
__global__ __launch_bounds__(256, 2)
void hqq_gemm2(const unsigned short* __restrict__ abf,
               const unsigned*       __restrict__ pw,
               const float*          __restrict__ sz,
               float*                __restrict__ out)
{
    const int bid = blockIdx.x;
    const int e   = bid / (MT * NT);
    const int rem = bid % (MT * NT);
    const int nt  = rem >> 2;
    const int mt  = rem & 3;

    __shared__ __align__(16) short Alds[BM * LDSS];  // [m][k] bf16
    __shared__ __align__(16) short Blds[BN * LDSS];  // [n][k] bf16 (transposed)

    const int tid = threadIdx.x;
    const int m0  = e * CAP + mt * BM;
    const int n0  = nt * BN;

    // A staging: row = tid>>2 (64 rows/pass, 2 passes), kq = tid&3 (octet of 8 bf16)
    const int a_kq  = tid & 3;
    const int a_row = tid >> 2;
    // B staging: thread owns one n column and half the k-range
    const int b_n   = tid & 127;
    const int b_h   = tid >> 7;

    const unsigned short* Ab = abf + (size_t)m0 * KDIM;
    const unsigned*       Wb = pw  + (size_t)e * K8 * NDIM + n0 + b_n;
    const float*          SZb = sz + (size_t)e * NGRP * (NDIM * 2) + (size_t)(n0 + b_n) * 2;

    f32x4 acc[4][4];
    #pragma unroll
    for (int i = 0; i < 4; ++i)
        #pragma unroll
        for (int j = 0; j < 4; ++j)
            acc[i][j] = (f32x4){0.f, 0.f, 0.f, 0.f};

    const int wave = tid >> 6;
    const int lane = tid & 63;
    const int wm = (wave >> 1) << 6;
    const int wn = (wave & 1) << 6;
    const int lr = lane & 15;
    const int lq = lane >> 4;

    for (int k0 = 0; k0 < KDIM; k0 += BK) {
        const int g = k0 >> 6;

        // ---- stage A: pure bf16x8 copies ----
        #pragma unroll
        for (int p = 0; p < 2; ++p) {
            const int row = a_row + p * 64;
            const bf16x8 v = *(const bf16x8*)(Ab + (size_t)row * KDIM + k0 + a_kq * 8);
            *(bf16x8*)&Alds[row * LDSS + a_kq * 8] = v;
        }

        // ---- stage B: 2 coalesced dword loads + nibble dequant ----
        const float2 s2 = *(const float2*)(SZb + (size_t)g * (NDIM * 2));
        const float s  = s2.x;
        const float z8 = s2.y - 8.f * s2.x;   // w = q*s + (z - 8s)
        const unsigned* wp = Wb + ((size_t)(k0 >> 3) + b_h * 2) * NDIM;
        const unsigned u0 = wp[0];
        const unsigned u1 = wp[NDIM];
        bf16x8 bb0, bb1;
        #pragma unroll
        for (int j = 0; j < 8; ++j) {
            bb0[j] = f2bf(fmaf((float)((u0 >> (4 * j)) & 15u), s, z8));
            bb1[j] = f2bf(fmaf((float)((u1 >> (4 * j)) & 15u), s, z8));
        }
        *(bf16x8*)&Blds[b_n * LDSS + b_h * 16]     = bb0;
        *(bf16x8*)&Blds[b_n * LDSS + b_h * 16 + 8] = bb1;

        __syncthreads();

        // ---- compute: 8 ds_read_b128 + 16 MFMA per wave ----
        bf16x8 af[4], bfv[4];
        #pragma unroll
        for (int i = 0; i < 4; ++i)
            af[i] = *(const bf16x8*)&Alds[(wm + i * 16 + lr) * LDSS + lq * 8];
        #pragma unroll
        for (int j = 0; j < 4; ++j)
            bfv[j] = *(const bf16x8*)&Blds[(wn + j * 16 + lr) * LDSS + lq * 8];
        #pragma unroll
        for (int i = 0; i < 4; ++i)
            #pragma unroll
            for (int j = 0; j < 4; ++j)
                acc[i][j] = __builtin_amdgcn_mfma_f32_16x16x32_bf16(af[i], bfv[j], acc[i][j], 0, 0, 0);

        __syncthreads();
    }

    const int orow0 = m0 + wm + lq * 4;
    const int ocol0 = n0 + wn + lr;
    #pragma unroll
    for (int i = 0; i < 4; ++i)
        #pragma unroll
        for (int r = 0; r < 4; ++r) {
            float* op = out + (size_t)(orow0 + i * 16 + r) * NDIM + ocol0;
            #pragma unroll
            for (int j = 0; j < 4; ++j)
                op[j * 16] = acc[i][j][r];
        }
}

// ---------------- Fallback (R1 kernel) if ws too small ----------------
__global__ __launch_bounds__(256, 2)
void hqq_gemm_fallback(const float* __restrict__ inp,
                       const int*   __restrict__ wq,
                       const float* __restrict__ sz,
                       float*       __restrict__ out)
{
    const int bid = blockIdx.x;
    const int e   = bid / (MT * NT);
    const int rem = bid % (MT * NT);
    const int nt  = rem >> 2;
    const int mt  = rem & 3;

    __shared__ __align__(16) short Alds[BM * LDSS];
    __shared__ __align__(16) short Blds[BN * LDSS];

    const int tid = threadIdx.x;
    const int m0  = e * CAP + mt * BM;
    const int n0  = nt * BN;

    const int a_kq  = tid & 7;
    const int a_row = tid >> 3;
    const int b_n   = tid & 127;
    const int b_h   = tid >> 7;

    const float* Ab  = inp + (size_t)m0 * KDIM;
    const int*   Wb  = wq  + (size_t)e * KDIM * NDIM + n0 + b_n;
    const float* SZb = sz  + (size_t)e * NGRP * (NDIM * 2) + (size_t)(n0 + b_n) * 2;

    f32x4 acc[4][4];
    #pragma unroll
    for (int i = 0; i < 4; ++i)
        #pragma unroll
        for (int j = 0; j < 4; ++j)
            acc[i][j] = (f32x4){0.f, 0.f, 0.f, 0.f};

    const int wave = tid >> 6;
    const int lane = tid & 63;
    const int wm = (wave >> 1) << 6;
    const int wn = (wave & 1) << 6;
    const int lr = lane & 15;
    const int lq = lane >> 4;

    for (int k0 = 0; k0 < KDIM; k0 += BK) {
        const int g = k0 >> 6;
        #pragma unroll
        for (int p = 0; p < 4; ++p) {
            const int row = a_row + p * 32;
            const float4 v = *(const float4*)(Ab + (size_t)row * KDIM + k0 + a_kq * 4);
            bf16x4 h;
            h[0] = f2bf(v.x); h[1] = f2bf(v.y); h[2] = f2bf(v.z); h[3] = f2bf(v.w);
            *(bf16x4*)&Alds[row * LDSS + a_kq * 4] = h;
        }
        const float2 s2 = *(const float2*)(SZb + (size_t)g * (NDIM * 2));
        const float s  = s2.x;
        const float z8 = s2.y - 8.f * s2.x;
        #pragma unroll
        for (int oo = 0; oo < 2; ++oo) {
            const int ko = b_h * 8 + oo * 16;
            const int* wp = Wb + (size_t)(k0 + ko) * NDIM;
            bf16x8 bb;
            #pragma unroll
            for (int j = 0; j < 8; ++j) {
                const float q = (float)wp[(size_t)j * NDIM];
                bb[j] = f2bf(fmaf(q, s, z8));
            }
            *(bf16x8*)&Blds[b_n * LDSS + ko] = bb;
        }
        __syncthreads();
        bf16x8 af[4], bfv[4];
        #pragma unroll
        for (int i = 0; i < 4; ++i)
            af[i] = *(const bf16x8*)&Alds[(wm + i * 16 + lr) * LDSS + lq * 8];
        #pragma unroll
        for (int j = 0; j < 4; ++j)
            bfv[j] = *(const bf16x8*)&Blds[(wn + j * 16 + lr) * LDSS + lq * 8];
        #pragma unroll
        for (int i = 0; i < 4; ++i)
            #pragma unroll
            for (int j = 0; j < 4; ++j)
                acc[i][j] = __builtin_amdgcn_mfma_f32_16x16x32_bf16(af[i], bfv[j], acc[i][j], 0, 0, 0);
        __syncthreads();
    }

    const int orow0 = m0 + wm + lq * 4;
    const int ocol0 = n0 + wn + lr;
    #pragma unroll
    for (int i = 0; i < 4; ++i)
        #pragma unroll
        for (int r = 0; r < 4; ++r) {
            float* op = out + (size_t)(orow0 + i * 16 + r) * NDIM + ocol0;
            #pragma unroll
            for (int j = 0; j < 4; ++j)
                op[j * 16] = acc[i][j][r];
        }
}

extern "C" void kernel_launch(void* const* d_in, const int* in_sizes, int n_in,
                              void* d_out, int out_size, void* d_ws, size_t ws_size,
                              hipStream_t stream) {
    const float* inp = (const float*)d_in[0];
    const int*   wq  = (const int*)d_in[2];
    const float* sz  = (const float*)d_in[3];
    float*       out = (float*)d_out;

    if (ws_size >= PACKED_BYTES + ABF_BYTES) {
        unsigned*       pw  = (unsigned*)d_ws;
        unsigned short* abf = (unsigned short*)((char*)d_ws + PACKED_BYTES);
        pack_kernel<<<dim3(PACK_BLOCKS + ACV_BLOCKS), dim3(256), 0, stream>>>(wq, inp, pw, abf);
        hqq_gemm2<<<dim3(NE * MT * NT), dim3(256), 0, stream>>>(abf, pw, sz, out);
    } else {
        hqq_gemm_fallback<<<dim3(NE * MT * NT), dim3(256), 0, stream>>>(inp, wq, sz, out);
    }
}